// Round 1
// baseline (1467.123 us; speedup 1.0000x reference)
//
#include <hip/hip_runtime.h>
#include <math.h>

#define T_LEN 51200
#define BATCH 1024
#define HDIM 128
#define NIT 100000

__device__ __forceinline__ int lower_bound_i(const int* __restrict__ a, int n, int v) {
    int lo = 0, hi = n;
    while (lo < hi) { int m = (lo + hi) >> 1; if (a[m] < v) lo = m + 1; else hi = m; }
    return lo;
}

// One block per batch row; 128 threads = one per feature.
__global__ __launch_bounds__(128) void pool_kernel(
    const int* __restrict__ item_idx, const int* __restrict__ item_seg,
    const int* __restrict__ ent_idx,  const int* __restrict__ ent_seg,
    const int* __restrict__ word_idx, const int* __restrict__ word_seg,
    const float* __restrict__ item_tab, const float* __restrict__ ent_tab,
    const float* __restrict__ word_tab,
    float* __restrict__ user, float* __restrict__ sums, float* __restrict__ sums2)
{
    const int b = blockIdx.x;
    const int h = threadIdx.x;
    float acc = 0.f;
    {
        int lo = lower_bound_i(item_seg, T_LEN, b);
        int hi = lower_bound_i(item_seg, T_LEN, b + 1);
        float s = 0.f;
        for (int t = lo; t < hi; ++t) s += item_tab[(size_t)item_idx[t] * HDIM + h];
        if (hi > lo) acc += s / (float)(hi - lo);
    }
    {
        int lo = lower_bound_i(ent_seg, T_LEN, b);
        int hi = lower_bound_i(ent_seg, T_LEN, b + 1);
        float s = 0.f;
        for (int t = lo; t < hi; ++t) s += ent_tab[(size_t)ent_idx[t] * HDIM + h];
        if (hi > lo) acc += s / (float)(hi - lo);
    }
    {
        int lo = lower_bound_i(word_seg, T_LEN, b);
        int hi = lower_bound_i(word_seg, T_LEN, b + 1);
        float s = 0.f;
        for (int t = lo; t < hi; ++t) s += word_tab[(size_t)word_idx[t] * HDIM + h];
        if (hi > lo) acc += s / (float)(hi - lo);
    }
    user[b * HDIM + h] = acc * (1.f / 3.f);
    if (h == 0) { sums[b] = 0.f; sums2[b] = 0.f; }
}

// Block tile: 128 cols x 64 rows. Thread tile: 4 cols x 8 rows.
// tx = tid&31 picks the 4-col group, ty = tid>>5 picks the 8-row group.
// user tile is transposed into LDS [h][r] (pad 68 keeps float4 alignment).
#define GK_PAD 68
__global__ __launch_bounds__(256) void gemm_kernel(
    const float* __restrict__ user, const float* __restrict__ w,
    const float* __restrict__ bias, float* __restrict__ lin,
    float* __restrict__ sums)
{
    __shared__ float uL[HDIM * GK_PAD];
    const int tid = threadIdx.x;
    const int tx = tid & 31;
    const int ty = tid >> 5;
    const int n0 = blockIdx.x * 128;
    const int r0 = blockIdx.y * 64;

    for (int i = tid; i < 64 * HDIM; i += 256) {
        int r = i >> 7, h = i & 127;
        uL[h * GK_PAD + r] = user[(r0 + r) * HDIM + h];
    }
    __syncthreads();

    const int n = n0 + tx * 4;
    const bool valid = (n < NIT);
    const float* wp = w + (valid ? n : 0);

    float acc[8][4];
    #pragma unroll
    for (int r = 0; r < 8; ++r)
        #pragma unroll
        for (int c = 0; c < 4; ++c) acc[r][c] = 0.f;

    #pragma unroll 8
    for (int h = 0; h < HDIM; ++h) {
        float4 wv = *(const float4*)(wp + (size_t)h * NIT);
        float4 u0 = *(const float4*)(&uL[h * GK_PAD + ty * 8]);
        float4 u1 = *(const float4*)(&uL[h * GK_PAD + ty * 8 + 4]);
        float u[8] = {u0.x, u0.y, u0.z, u0.w, u1.x, u1.y, u1.z, u1.w};
        float wc[4] = {wv.x, wv.y, wv.z, wv.w};
        #pragma unroll
        for (int r = 0; r < 8; ++r)
            #pragma unroll
            for (int c = 0; c < 4; ++c)
                acc[r][c] = fmaf(u[r], wc[c], acc[r][c]);
    }

    float bc[4] = {0.f, 0.f, 0.f, 0.f};
    if (valid) {
        float4 bv = *(const float4*)(bias + n);
        bc[0] = bv.x; bc[1] = bv.y; bc[2] = bv.z; bc[3] = bv.w;
    }

    #pragma unroll
    for (int r = 0; r < 8; ++r) {
        const int row = r0 + ty * 8 + r;
        float v0 = acc[r][0] + bc[0];
        float v1 = acc[r][1] + bc[1];
        float v2 = acc[r][2] + bc[2];
        float v3 = acc[r][3] + bc[3];
        float e = 0.f;
        if (valid) {
            float4 o = make_float4(v0, v1, v2, v3);
            *(float4*)(lin + (size_t)row * NIT + n) = o;
            e = __expf(v0) + __expf(v1) + __expf(v2) + __expf(v3);
        }
        #pragma unroll
        for (int m = 1; m < 32; m <<= 1) e += __shfl_xor(e, m);
        if (tx == 0) atomicAdd(&sums[row], e);
    }
}

// In-place: lin -> probs; accumulate sum(exp(probs)) per row.
__global__ __launch_bounds__(256) void softmax_kernel(
    float* __restrict__ probs, const float* __restrict__ sums, float* __restrict__ sums2)
{
    const int b = blockIdx.y;
    const float rinv = 1.0f / sums[b];
    float4* rowp = (float4*)(probs + (size_t)b * NIT);
    float part = 0.f;
    const int end = (blockIdx.x + 1) * 6250;  // 25000 float4 per row, 4 chunks
    for (int i = blockIdx.x * 6250 + threadIdx.x; i < end; i += 256) {
        float4 v = rowp[i];
        v.x = __expf(v.x) * rinv;
        v.y = __expf(v.y) * rinv;
        v.z = __expf(v.z) * rinv;
        v.w = __expf(v.w) * rinv;
        rowp[i] = v;
        part += __expf(v.x) + __expf(v.y) + __expf(v.z) + __expf(v.w);
    }
    #pragma unroll
    for (int m = 1; m < 64; m <<= 1) part += __shfl_xor(part, m);
    if ((threadIdx.x & 63) == 0) atomicAdd(&sums2[b], part);
}

__global__ __launch_bounds__(256) void loss_kernel(
    const float* __restrict__ probs, const int* __restrict__ labels,
    const float* __restrict__ sums2, float* __restrict__ out)
{
    __shared__ float red[256];
    float t = 0.f;
    for (int b = threadIdx.x; b < BATCH; b += 256) {
        int lab = labels[b];
        float p = probs[(size_t)b * NIT + lab];
        t += p - logf(sums2[b]);
        out[(size_t)BATCH * NIT + b] = (float)lab;  // labels output as f32
    }
    red[threadIdx.x] = t;
    __syncthreads();
    for (int s = 128; s > 0; s >>= 1) {
        if (threadIdx.x < s) red[threadIdx.x] += red[threadIdx.x + s];
        __syncthreads();
    }
    if (threadIdx.x == 0) out[(size_t)BATCH * NIT + BATCH] = -red[0] / (float)BATCH;
}

extern "C" void kernel_launch(void* const* d_in, const int* in_sizes, int n_in,
                              void* d_out, int out_size, void* d_ws, size_t ws_size,
                              hipStream_t stream)
{
    const int* item_idx = (const int*)d_in[0];
    const int* item_seg = (const int*)d_in[1];
    const int* ent_idx  = (const int*)d_in[2];
    const int* ent_seg  = (const int*)d_in[3];
    const int* word_idx = (const int*)d_in[4];
    const int* word_seg = (const int*)d_in[5];
    const int* labels   = (const int*)d_in[6];
    const float* item_tab = (const float*)d_in[7];
    const float* ent_tab  = (const float*)d_in[8];
    const float* word_tab = (const float*)d_in[9];
    const float* rec_w    = (const float*)d_in[10];
    const float* rec_b    = (const float*)d_in[11];
    float* out = (float*)d_out;

    float* user  = (float*)d_ws;            // 1024*128
    float* sums  = user + BATCH * HDIM;     // 1024
    float* sums2 = sums + BATCH;            // 1024

    pool_kernel<<<BATCH, 128, 0, stream>>>(item_idx, item_seg, ent_idx, ent_seg,
                                           word_idx, word_seg, item_tab, ent_tab,
                                           word_tab, user, sums, sums2);

    // lin is staged in d_out's probs region (overwritten in place by softmax_kernel)
    gemm_kernel<<<dim3((NIT + 127) / 128, BATCH / 64), 256, 0, stream>>>(
        user, rec_w, rec_b, out, sums);

    softmax_kernel<<<dim3(4, BATCH), 256, 0, stream>>>(out, sums, sums2);

    loss_kernel<<<1, 256, 0, stream>>>(out, labels, sums2, out);
}